// Round 4
// baseline (212.221 us; speedup 1.0000x reference)
//
#include <hip/hip_runtime.h>
#include <math.h>

// Problem constants (fixed by reference)
#define GRIDN   14
#define BOXN    2
#define LABELN  20
#define ALL_BOX 10          // 5*BOXN
#define CCH     30          // ALL_BOX + LABELN channels per cell

__global__ void yolo_zero_kernel(float* out, int n) {
    int i = blockIdx.x * blockDim.x + threadIdx.x;
    if (i < n) out[i] = 0.0f;
}

// m13-copy regime: no LDS staging, no barriers in the hot path. Each thread
// owns one cell and issues 30 independent global_load_dwordx2 (8B-aligned:
// cell base = 120B). Per-instr lane stride is 120B but the wave's loads
// collectively cover each 64B line exactly once -> L1/MSHR merge keeps
// HBM traffic exact. High occupancy (no LDS, VGPR-capped) supplies the MLP
// that the global_load_lds DMA path failed to deliver (R2/R3 post-mortem).
__global__ __launch_bounds__(256, 4) void yolo_loss_kernel(
    const float* __restrict__ preds,
    const float* __restrict__ truths,
    float* __restrict__ out,
    int ncells)
{
#pragma clang fp contract(off)
    __shared__ float wsum[4];

    const int tid  = threadIdx.x;
    const int wave = tid >> 6;
    const int lane = tid & 63;

    const long long cell = (long long)blockIdx.x * blockDim.x + tid;

    float cell_loss = 0.0f;
    if (cell < ncells) {
        const float2* pp = (const float2*)(preds  + cell * CCH);
        const float2* tp = (const float2*)(truths + cell * CCH);

        // Issue ALL loads up front (independent -> deep MLP per wave)
        float2 P[15];
#pragma unroll
        for (int i = 0; i < 15; ++i) P[i] = pp[i];
        float2 T0 = tp[0], T1 = tp[1], T2 = tp[2];   // t[0..5] (t[5] unused)
        float2 TL[10];
#pragma unroll
        for (int i = 0; i < 10; ++i) TL[i] = tp[5 + i];  // t[10..29]

        const float CELL = (float)(1.0 / (double)GRIDN);

        const float tx = T0.x, ty = T0.y, tw = T1.x, th_ = T1.y, tconf = T2.x;
        const bool obj = tconf > 0.0f;

        // Truth box (scaled center, half-extent) — same op order as reference
        const float tcx = CELL * tx, tcy = CELL * ty;
        const float thx = tw * 0.5f, thy = th_ * 0.5f;
        const float tltx = tcx - thx, tlty = tcy - thy;
        const float trbx = tcx + thx, trby = tcy + thy;
        const float ta = (trbx - tltx) * (trby - tlty);

        // pred boxes: p[0..4] = P0.x P0.y P1.x P1.y P2.x ; p[5..9] = P2.y P3.x P3.y P4.x P4.y
        float pb[BOXN][5];
        pb[0][0] = P[0].x; pb[0][1] = P[0].y; pb[0][2] = P[1].x; pb[0][3] = P[1].y; pb[0][4] = P[2].x;
        pb[1][0] = P[2].y; pb[1][1] = P[3].x; pb[1][2] = P[3].y; pb[1][3] = P[4].x; pb[1][4] = P[4].y;

        float iou[BOXN], conf[BOXN];
#pragma unroll
        for (int b = 0; b < BOXN; ++b) {
            const float bx = pb[b][0], by = pb[b][1];
            const float bw = pb[b][2], bh = pb[b][3];
            conf[b] = pb[b][4];
            const float pcx = CELL * bx, pcy = CELL * by;
            const float phx = bw * 0.5f, phy = bh * 0.5f;
            const float pltx = pcx - phx, plty = pcy - phy;
            const float prbx = pcx + phx, prby = pcy + phy;
            const float ltx = fmaxf(pltx, tltx), lty = fmaxf(plty, tlty);
            const float rbx = fminf(prbx, trbx), rby = fminf(prby, trby);
            const float whx = fmaxf(rbx - ltx, 0.0f);
            const float why = fmaxf(rby - lty, 0.0f);
            const float inter = whx * why;
            const float pa = (prbx - pltx) * (prby - plty);
            iou[b] = inter / (pa + ta - inter);
        }

        const float max_iou = fmaxf(iou[0], iou[1]);
        // jnp argmax first-occurrence + tie rule (n_tied>1 -> conf argmax)
        int resp;
        if (iou[0] == iou[1]) resp = (conf[0] >= conf[1]) ? 0 : 1;
        else                  resp = (iou[0] > iou[1]) ? 0 : 1;

        const float* prr = pb[resp];

        const float dcx = prr[0] - tx;
        const float dcy = prr[1] - ty;
        const float center = dcx * dcx + dcy * dcy;

        const float dsx = sqrtf(prr[2]) - sqrtf(tw);
        const float dsy = sqrtf(prr[3]) - sqrtf(th_);
        const float size = dsx * dsx + dsy * dsy;

        const float dconf = prr[4] - max_iou;
        const float conf_resp = dconf * dconf;

        const float c_other = conf[1 - resp];
        const float conf_noresp = c_other * c_other;

        const float conf_noobj = conf[0] * conf[0] + conf[1] * conf[1];

        // Label loss, same sequential k order as reference (x then y per pair)
        float label = 0.0f;
#pragma unroll
        for (int i = 0; i < 10; ++i) {
            const float dx = P[5 + i].x - TL[i].x;
            label += dx * dx;
            const float dy = P[5 + i].y - TL[i].y;
            label += dy * dy;
        }

        const float w  = obj ? 1.0f : 0.0f;
        const float nw = obj ? 0.0f : 1.0f;
        cell_loss = w * (5.0f * (center + size) + conf_resp + 0.5f * conf_noresp + label)
                  + nw * (0.5f * conf_noobj);
    }

    // Block reduction: wave64 shuffle -> LDS across 4 waves -> one atomic per block
    float v = cell_loss;
#pragma unroll
    for (int off = 32; off > 0; off >>= 1) v += __shfl_down(v, off, 64);
    if (lane == 0) wsum[wave] = v;
    __syncthreads();
    if (tid == 0) {
        const float s = (wsum[0] + wsum[1]) + (wsum[2] + wsum[3]);
        atomicAdd(out, s * (1.0f / 4096.0f));
    }
}

extern "C" void kernel_launch(void* const* d_in, const int* in_sizes, int n_in,
                              void* d_out, int out_size, void* d_ws, size_t ws_size,
                              hipStream_t stream) {
    const float* preds  = (const float*)d_in[0];
    const float* truths = (const float*)d_in[1];
    float* out = (float*)d_out;

    const int ncells = in_sizes[0] / CCH;          // 4096*14*14 = 802816
    const int blocks = (ncells + 255) / 256;       // 3136 (exact)

    // d_out is re-poisoned before every timed launch -> zero it on-stream first.
    yolo_zero_kernel<<<(out_size + 255) / 256, 256, 0, stream>>>(out, out_size);
    yolo_loss_kernel<<<blocks, 256, 0, stream>>>(preds, truths, out, ncells);
}